// Round 12
// baseline (1767.451 us; speedup 1.0000x reference)
//
#include <hip/hip_runtime.h>

typedef short shortx8 __attribute__((ext_vector_type(8)));   // 8 bf16 (4 VGPRs)
typedef short shortx4 __attribute__((ext_vector_type(4)));   // 4 bf16 (8B)
typedef float floatx4 __attribute__((ext_vector_type(4)));
typedef float floatx16 __attribute__((ext_vector_type(16)));
typedef unsigned short u16;
typedef unsigned int u32;

#define GLB(x) ((const __attribute__((address_space(1))) void*)(x))
#define LDSC(x) ((__attribute__((address_space(3))) void*)(x))
// Rendezvous WITHOUT a waitcnt drain: __builtin_amdgcn_s_barrier carries no
// memory clobber (the asm-"memory" version makes SIInsertWaitcnts emit
// vmcnt(0) before every barrier, defeating the counted-vmcnt pipeline).
// sched_barrier(0) pins compile-time ordering across the barrier instead.
#define BARRIER()                                  \
  do {                                             \
    __builtin_amdgcn_sched_barrier(0);             \
    __builtin_amdgcn_s_barrier();                  \
    __builtin_amdgcn_sched_barrier(0);             \
  } while (0)
#define WAITV8() asm volatile("s_waitcnt vmcnt(8)" ::: "memory")

__device__ __forceinline__ float bf2f(u16 u) {
  unsigned x = ((unsigned)u) << 16;
  float f;
  __builtin_memcpy(&f, &x, 4);
  return f;
}
__device__ __forceinline__ u16 f2bf(float f) {
  unsigned x;
  __builtin_memcpy(&x, &f, 4);
  x += 0x7fffu + ((x >> 16) & 1u);   // RNE
  return (u16)(x >> 16);
}
__device__ __forceinline__ u32 pk_bf16(float lo, float hi) {
  u32 r;
  asm("v_cvt_pk_bf16_f32 %0, %1, %2" : "=v"(r) : "v"(lo), "v"(hi));
  return r;
}

// ---------------------------------------------------------------------------
// fp32 -> bf16 flat cast (X)
__global__ __launch_bounds__(256) void cast_bf16(const float* __restrict__ src,
                                                 u16* __restrict__ dst) {
  const size_t i = ((size_t)blockIdx.x * 256 + threadIdx.x) << 3;
  floatx4 a = *(const floatx4*)(src + i);
  floatx4 b = *(const floatx4*)(src + i + 4);
  shortx8 o;
#pragma unroll
  for (int e = 0; e < 4; ++e) {
    o[e] = (short)f2bf(a[e]);
    o[e + 4] = (short)f2bf(b[e]);
  }
  *(shortx8*)(dst + i) = o;
}

// ---------------------------------------------------------------------------
// fp32 [R][C] -> bf16 [C][R] tile transpose+cast (64x64 tiles via LDS).
// perm=1: W1 column interleave — dest row order [qkv(9216) | m1/m2 in
// 128-col pairs] so each 256-col GEMM tile holds matching m1/m2 chunks.
__global__ __launch_bounds__(256) void transpose_cast(const float* __restrict__ src,
                                                      u16* __restrict__ dst,
                                                      int R, int C, int perm) {
  __shared__ u16 T[64 * 72];
  const int tiles_c = C >> 6;
  const int r0 = (blockIdx.x / tiles_c) << 6;
  const int c0 = (blockIdx.x % tiles_c) << 6;
  const int tid = threadIdx.x;
  const int rl = tid >> 4;
  const int cb = (tid & 15) << 2;
#pragma unroll
  for (int rr = 0; rr < 4; ++rr) {
    const int row = rr * 16 + rl;
    floatx4 v = *(const floatx4*)(src + (size_t)(r0 + row) * C + c0 + cb);
#pragma unroll
    for (int i = 0; i < 4; ++i) T[(cb + i) * 72 + row] = f2bf(v[i]);
  }
  __syncthreads();
  int dbase = c0;
  if (perm && c0 >= 9216) {
    if (c0 < 21504) { const int u = c0 - 9216;  dbase = 9216 + ((u >> 7) << 8) + (u & 64); }
    else            { const int u = c0 - 21504; dbase = 9216 + ((u >> 7) << 8) + 128 + (u & 64); }
  }
#pragma unroll
  for (int ii = 0; ii < 2; ++ii) {
    const int chunk = tid + (ii << 8);
    const int cr = chunk >> 3;
    const int r8 = (chunk & 7) << 3;
    shortx8 v = *(const shortx8*)(T + cr * 72 + r8);
    *(shortx8*)(dst + (size_t)(dbase + cr) * R + r0 + r8) = v;
  }
}

// ---------------------------------------------------------------------------
// 256x256 8-phase bf16 GEMM.  B^T layout: C = A[M][Kchunk] * B^T([N][Kchunk]).
// 16x16x32 MFMA.  LDS: 2buf x {A,B} x {k0,k1} units of [256][32] (16KB).
// 4 phases/K-tile, 1 stage-unit/phase 1.5 tiles ahead, vmcnt(8) twice/tile,
// __builtin s_barrier (NO drain) + sched_barrier pinning.
// MODE 0 (GEMM1 fused): bn<36 -> bf16 qkv to H (stride 9216); bn>=36 -> MLP
// tile with balanced bidirectional silu(m1)*m2 exchange.
// MODE 1: fp32 partial (split-K via blockIdx.y) for GEMM2.
template <int MODE>
__global__ __launch_bounds__(512, 2) void gemm8(const u16* __restrict__ A,
                                                const u16* __restrict__ B,
                                                void* __restrict__ Cout,
                                                u16* __restrict__ CC2,
                                                int M, int N, int K, int Ksub) {
  __shared__ u16 lds[8 * 8192];  // [buf][mat][ks][256*32] = 128 KiB

  const int nbm = M >> 8;
  const int nwg = nbm * (N >> 8);
  const int cpx = nwg >> 3;
  const int wg = ((int)blockIdx.x & 7) * cpx + ((int)blockIdx.x >> 3);
  const int bm = wg % nbm;
  const int bn = wg / nbm;
  const int koff = (int)blockIdx.y * Ksub;

  const int tid = threadIdx.x;
  const int lane = tid & 63;
  const int w = tid >> 6;
  const int wm = w >> 2;
  const int wn = w & 3;
  const int l15 = lane & 15;
  const int l4 = lane >> 4;
  const int NT = Ksub >> 6;

  const int lrow = lane >> 2;
  const int lblk = lane & 3;

#define UNIT(buf, mat, ks) (lds + (((buf) * 4 + (mat) * 2 + (ks)) << 13))

  const u16* Abase = A + (size_t)bm * 256 * K + koff;
  const u16* Bbase = B + (size_t)bn * 256 * K + koff;

  auto STAGE = [&](int mat, int ks, int buf, int t) {
    const u16* gb = mat ? Bbase : Abase;
#pragma unroll
    for (int j = 0; j < 2; ++j) {
      const int row = (w * 2 + j) * 16 + lrow;
      const int sblk = lblk ^ ((row >> 1) & 3);
      const u16* src = gb + (size_t)row * K + (t << 6) + (ks << 5) + (sblk << 3);
      __builtin_amdgcn_global_load_lds(GLB(src),
                                       LDSC(UNIT(buf, mat, ks) + ((w * 2 + j) << 9)),
                                       16, 0, 0);
    }
  };
  auto LDA = [&](int mf, int ks, int buf) -> shortx8 {
    const int row = wm * 128 + mf * 16 + l15;
    return *(const shortx8*)(UNIT(buf, 0, ks) + row * 32 + ((l4 ^ ((row >> 1) & 3)) << 3));
  };
  auto LDB = [&](int nf, int ks, int buf) -> shortx8 {
    const int row = wn * 64 + nf * 16 + l15;
    return *(const shortx8*)(UNIT(buf, 1, ks) + row * 32 + ((l4 ^ ((row >> 1) & 3)) << 3));
  };

  floatx4 acc[8][4] = {};

  STAGE(0, 0, 0, 0); STAGE(1, 0, 0, 0);
  STAGE(0, 1, 0, 0); STAGE(1, 1, 0, 0);
  STAGE(0, 0, 1, 1); STAGE(1, 0, 1, 1);
  WAITV8();
  BARRIER();

#pragma unroll 2
  for (int T = 0; T < NT; ++T) {
    const int cur = T & 1, nxt = cur ^ 1;
    const int t1 = (T + 1 < NT) ? T + 1 : NT - 1;
    const int t2 = (T + 2 < NT) ? T + 2 : NT - 1;
    shortx8 af[4], bf[4];

    // ---- q0: C-half0 x k0;  stage A-k1 of T+1 -> buf nxt
#pragma unroll
    for (int m = 0; m < 4; ++m) af[m] = LDA(m, 0, cur);
#pragma unroll
    for (int n = 0; n < 4; ++n) bf[n] = LDB(n, 0, cur);
    STAGE(0, 1, nxt, t1);
    BARRIER();
    __builtin_amdgcn_s_setprio(1);
#pragma unroll
    for (int m = 0; m < 4; ++m)
#pragma unroll
      for (int n = 0; n < 4; ++n)
        acc[m][n] = __builtin_amdgcn_mfma_f32_16x16x32_bf16(af[m], bf[n], acc[m][n], 0, 0, 0);
    __builtin_amdgcn_s_setprio(0);
    BARRIER();

    // ---- q1: C-half1 x k0;  stage B-k1 of T+1
#pragma unroll
    for (int m = 0; m < 4; ++m) af[m] = LDA(4 + m, 0, cur);
    STAGE(1, 1, nxt, t1);
    BARRIER();
    __builtin_amdgcn_s_setprio(1);
#pragma unroll
    for (int m = 0; m < 4; ++m)
#pragma unroll
      for (int n = 0; n < 4; ++n)
        acc[4 + m][n] = __builtin_amdgcn_mfma_f32_16x16x32_bf16(af[m], bf[n], acc[4 + m][n], 0, 0, 0);
    __builtin_amdgcn_s_setprio(0);
    WAITV8();
    BARRIER();

    // ---- q2: C-half0 x k1;  stage A-k0 of T+2 -> buf cur
#pragma unroll
    for (int m = 0; m < 4; ++m) af[m] = LDA(m, 1, cur);
#pragma unroll
    for (int n = 0; n < 4; ++n) bf[n] = LDB(n, 1, cur);
    STAGE(0, 0, cur, t2);
    BARRIER();
    __builtin_amdgcn_s_setprio(1);
#pragma unroll
    for (int m = 0; m < 4; ++m)
#pragma unroll
      for (int n = 0; n < 4; ++n)
        acc[m][n] = __builtin_amdgcn_mfma_f32_16x16x32_bf16(af[m], bf[n], acc[m][n], 0, 0, 0);
    __builtin_amdgcn_s_setprio(0);
    BARRIER();

    // ---- q3: C-half1 x k1;  stage B-k0 of T+2
#pragma unroll
    for (int m = 0; m < 4; ++m) af[m] = LDA(4 + m, 1, cur);
    STAGE(1, 0, cur, t2);
    BARRIER();
    __builtin_amdgcn_s_setprio(1);
#pragma unroll
    for (int m = 0; m < 4; ++m)
#pragma unroll
      for (int n = 0; n < 4; ++n)
        acc[4 + m][n] = __builtin_amdgcn_mfma_f32_16x16x32_bf16(af[m], bf[n], acc[4 + m][n], 0, 0, 0);
    __builtin_amdgcn_s_setprio(0);
    WAITV8();
    BARRIER();
  }

  const int orow0 = bm * 256 + wm * 128 + (l4 << 2);
  if (MODE == 0) {
    if (bn < 36) {
      u16* C = (u16*)Cout;
      const int ocol0 = bn * 256 + wn * 64 + l15;
#pragma unroll
      for (int m = 0; m < 8; ++m)
#pragma unroll
        for (int n = 0; n < 4; ++n)
#pragma unroll
          for (int r = 0; r < 4; ++r)
            C[(size_t)(orow0 + m * 16 + r) * 9216 + ocol0 + n * 16] = f2bf(acc[m][n][r]);
    } else {
      // Balanced MLP exchange: per pair region 32KB = [m2 stash | m1 stash]
      __syncthreads();                 // full drain; LDS reusable
      float* buf = (float*)lds + (wm * 2 + (wn & 1)) * 8192;
      if (wn >= 2) {
#pragma unroll
        for (int m = 0; m < 4; ++m)
#pragma unroll
          for (int n = 0; n < 4; ++n) {
            const int chunk = (m * 4 + l4) ^ (l15 & 7);
            *(floatx4*)(buf + (((n * 16 + l15) << 4) + chunk) * 4) = acc[m][n];
          }
      } else {
#pragma unroll
        for (int m = 0; m < 4; ++m)
#pragma unroll
          for (int n = 0; n < 4; ++n) {
            const int chunk = (m * 4 + l4) ^ (l15 & 7);
            *(floatx4*)(buf + 4096 + (((n * 16 + l15) << 4) + chunk) * 4) = acc[4 + m][n];
          }
      }
      __syncthreads();
      const int gcol0 = 3072 + (bn - 36) * 128 + (wn & 1) * 64 + l15;
      if (wn < 2) {
#pragma unroll
        for (int m = 0; m < 4; ++m)
#pragma unroll
          for (int n = 0; n < 4; ++n) {
            const int chunk = (m * 4 + l4) ^ (l15 & 7);
            const floatx4 m2v = *(const floatx4*)(buf + (((n * 16 + l15) << 4) + chunk) * 4);
#pragma unroll
            for (int r = 0; r < 4; ++r) {
              const float m1 = acc[m][n][r];
              const float sg = 1.0f / (1.0f + exp2f(-1.4426950408889634f * m1));
              CC2[(size_t)(orow0 + m * 16 + r) * 15360 + gcol0 + n * 16] =
                  f2bf(m1 * sg * m2v[r]);
            }
          }
      } else {
#pragma unroll
        for (int m = 0; m < 4; ++m)
#pragma unroll
          for (int n = 0; n < 4; ++n) {
            const int chunk = (m * 4 + l4) ^ (l15 & 7);
            const floatx4 m1v = *(const floatx4*)(buf + 4096 + (((n * 16 + l15) << 4) + chunk) * 4);
#pragma unroll
            for (int r = 0; r < 4; ++r) {
              const float m1 = m1v[r];
              const float sg = 1.0f / (1.0f + exp2f(-1.4426950408889634f * m1));
              CC2[(size_t)(orow0 + (4 + m) * 16 + r) * 15360 + gcol0 + n * 16] =
                  f2bf(m1 * sg * acc[4 + m][n][r]);
            }
          }
      }
    }
  } else {
    float* C = (float*)Cout + (size_t)blockIdx.y * M * N;
    const int ocol0 = bn * 256 + wn * 64 + l15;
#pragma unroll
    for (int m = 0; m < 8; ++m)
#pragma unroll
      for (int n = 0; n < 4; ++n)
#pragma unroll
        for (int r = 0; r < 4; ++r)
          C[(size_t)(orow0 + m * 16 + r) * N + ocol0 + n * 16] = acc[m][n][r];
  }
}
#undef UNIT

// ---------------------------------------------------------------------------
// Split-K reduction: out = p0+p1+p2+p3 + bias
__global__ __launch_bounds__(256) void reduce_bias(const float* __restrict__ P,
                                                   const float* __restrict__ bias,
                                                   float* __restrict__ out) {
  const size_t base = ((size_t)blockIdx.x * 256 + threadIdx.x) << 2;
  const size_t stride = (size_t)4096 * 3072;
  floatx4 a = *(const floatx4*)(P + base);
  floatx4 b = *(const floatx4*)(P + stride + base);
  floatx4 c = *(const floatx4*)(P + 2 * stride + base);
  floatx4 d = *(const floatx4*)(P + 3 * stride + base);
  floatx4 bb = *(const floatx4*)(bias + (base % 3072));
  *(floatx4*)(out + base) = a + b + c + d + bb;
}

// ---------------------------------------------------------------------------
// RMSNorm + RoPE + scale fold for Q/K, V transpose to [H][D][S].
#define QSCALE (0.08838834764831845f * 1.4426950408889634f)  // 1/sqrt(128) * log2(e)

__global__ __launch_bounds__(256, 2) void qkv_prep(
    const u16* __restrict__ H, const float* __restrict__ cosb,
    const float* __restrict__ sinb, const float* __restrict__ nqw,
    const float* __restrict__ nkw, u16* __restrict__ Qo, u16* __restrict__ Ko,
    u16* __restrict__ Vo) {
  __shared__ u16 VT[128 * 72];
  const int head = blockIdx.y;
  const int t0 = blockIdx.x << 6;
  const int tid = threadIdx.x;
  const int tl = tid >> 2;
  const int db = (tid & 3) << 5;
  const int token = t0 + tl;

  const u16* hp = H + (size_t)token * 9216 + head * 128 + db;
  shortx8 qv[4], kvv[4], vv[4];
#pragma unroll
  for (int i = 0; i < 4; ++i) {
    qv[i] = *(const shortx8*)(hp + i * 8);
    kvv[i] = *(const shortx8*)(hp + 3072 + i * 8);
    vv[i] = *(const shortx8*)(hp + 6144 + i * 8);
  }
  float qx[32], kx[32];
  float sq = 0.f, sk = 0.f;
#pragma unroll
  for (int i = 0; i < 4; ++i)
#pragma unroll
    for (int j = 0; j < 8; ++j) {
      float a = bf2f((u16)qv[i][j]); qx[i * 8 + j] = a; sq += a * a;
      float b = bf2f((u16)kvv[i][j]); kx[i * 8 + j] = b; sk += b * b;
    }
  sq += __shfl_xor(sq, 1); sq += __shfl_xor(sq, 2);
  sk += __shfl_xor(sk, 1); sk += __shfl_xor(sk, 2);
  const float rq = rsqrtf(sq * (1.0f / 128.0f) + 1e-5f);
  const float rk = rsqrtf(sk * (1.0f / 128.0f) + 1e-5f);

  shortx8 oqv[4], okv[4];
#pragma unroll
  for (int p = 0; p < 16; ++p) {
    const float c = cosb[(size_t)token * 64 + (db >> 1) + p];
    const float s = sinb[(size_t)token * 64 + (db >> 1) + p];
    const int vi = p >> 2, vj = (p & 3) << 1;
    float a1 = qx[2 * p] * rq * nqw[db + 2 * p];
    float a2 = qx[2 * p + 1] * rq * nqw[db + 2 * p + 1];
    oqv[vi][vj] = (short)f2bf((a1 * c - a2 * s) * QSCALE);
    oqv[vi][vj + 1] = (short)f2bf((a2 * c + a1 * s) * QSCALE);
    float b1 = kx[2 * p] * rk * nkw[db + 2 * p];
    float b2 = kx[2 * p + 1] * rk * nkw[db + 2 * p + 1];
    okv[vi][vj] = (short)f2bf(b1 * c - b2 * s);
    okv[vi][vj + 1] = (short)f2bf(b2 * c + b1 * s);
  }
  {
    u16* qo = Qo + (size_t)head * 4096 * 128 + (size_t)token * 128 + db;
    u16* ko = Ko + (size_t)head * 4096 * 128 + (size_t)token * 128 + db;
#pragma unroll
    for (int i = 0; i < 4; ++i) {
      *(shortx8*)(qo + i * 8) = oqv[i];
      *(shortx8*)(ko + i * 8) = okv[i];
    }
  }
#pragma unroll
  for (int i = 0; i < 4; ++i)
#pragma unroll
    for (int j = 0; j < 8; ++j) VT[(db + i * 8 + j) * 72 + tl] = (u16)vv[i][j];
  __syncthreads();
#pragma unroll
  for (int ii = 0; ii < 4; ++ii) {
    const int chunk = tid + (ii << 8);
    const int d = chunk >> 3;
    const int j8 = (chunk & 7) << 3;
    shortx8 v = *(const shortx8*)(VT + d * 72 + j8);
    *(shortx8*)(Vo + (size_t)head * 128 * 4096 + (size_t)d * 4096 + t0 + j8) = v;
  }
}

// ---------------------------------------------------------------------------
// Flash attention, 32x32x16 MFMA, register-resident P (R11-verified).
__global__ __launch_bounds__(256, 2) void attn_kernel(const u16* __restrict__ Qg,
                                                      const u16* __restrict__ Kg,
                                                      const u16* __restrict__ Vg,
                                                      u16* __restrict__ CC) {
  __shared__ u16 Ks[128 * 128];   // [kv][d] swizzled
  __shared__ u16 Vs[128 * 128];   // [d][kv] swizzled

  const int head = blockIdx.y;
  const int q0 = blockIdx.x << 7;
  const int tid = threadIdx.x;
  const int lane = tid & 63;
  const int wave = tid >> 6;
  const int l31 = lane & 31;
  const int kh = lane >> 5;

  const u16* Qh = Qg + (size_t)head * 4096 * 128;
  const u16* Kh = Kg + (size_t)head * 4096 * 128;
  const u16* Vh = Vg + (size_t)head * 128 * 4096;

  const int qrow = q0 + wave * 32 + l31;
  shortx8 qf[8];
#pragma unroll
  for (int ks = 0; ks < 8; ++ks)
    qf[ks] = *(const shortx8*)(Qh + (size_t)qrow * 128 + ks * 16 + kh * 8);

  floatx16 ot[4] = {};
  float mrun = -1e30f, lrun = 0.0f;

  for (int s0 = 0; s0 < 4096; s0 += 128) {
#pragma unroll
    for (int i = 0; i < 8; ++i) {
      const int c = wave * 8 + i;
      const int row = c * 4 + (lane >> 4);
      const int blk = (lane & 15) ^ (row & 7);
      __builtin_amdgcn_global_load_lds(GLB(Kh + (size_t)(s0 + row) * 128 + blk * 8),
                                       LDSC(Ks + c * 512), 16, 0, 0);
    }
#pragma unroll
    for (int i = 0; i < 8; ++i) {
      const int c = wave * 8 + i;
      const int row = c * 4 + (lane >> 4);
      const int blk = (lane & 15) ^ (row & 7);
      __builtin_amdgcn_global_load_lds(GLB(Vh + (size_t)row * 4096 + s0 + blk * 8),
                                       LDSC(Vs + c * 512), 16, 0, 0);
    }
    __syncthreads();

    floatx16 st[4] = {};
    __builtin_amdgcn_s_setprio(1);
#pragma unroll
    for (int kvt = 0; kvt < 4; ++kvt) {
      const int krow = kvt * 32 + l31;
#pragma unroll
      for (int ks = 0; ks < 8; ++ks) {
        shortx8 kf = *(const shortx8*)(Ks + krow * 128 + (((ks * 2 + kh) ^ (krow & 7)) << 3));
        st[kvt] = __builtin_amdgcn_mfma_f32_32x32x16_bf16(kf, qf[ks], st[kvt], 0, 0, 0);
      }
    }
    __builtin_amdgcn_s_setprio(0);

    float vmax = st[0][0];
#pragma unroll
    for (int t = 0; t < 4; ++t)
#pragma unroll
      for (int r = 0; r < 16; ++r) vmax = fmaxf(vmax, st[t][r]);
    vmax = fmaxf(vmax, __shfl_xor(vmax, 32));
    const float mn = fmaxf(mrun, vmax);
    const float alpha = exp2f(mrun - mn);
    mrun = mn;

    float rs = 0.0f;
#pragma unroll
    for (int t = 0; t < 4; ++t)
#pragma unroll
      for (int r = 0; r < 16; ++r) {
        const float p = exp2f(st[t][r] - mn);
        st[t][r] = p;
        rs += p;
      }
    rs += __shfl_xor(rs, 32);
    lrun = lrun * alpha + rs;
    if (__any(alpha < 1.0f)) {
#pragma unroll
      for (int dt = 0; dt < 4; ++dt)
#pragma unroll
        for (int r = 0; r < 16; ++r) ot[dt][r] *= alpha;
    }

    u32 w[4][8];
#pragma unroll
    for (int t = 0; t < 4; ++t)
#pragma unroll
      for (int q = 0; q < 4; ++q) {
        w[t][2 * q] = pk_bf16(st[t][4 * q], st[t][4 * q + 1]);
        w[t][2 * q + 1] = pk_bf16(st[t][4 * q + 2], st[t][4 * q + 3]);
      }

#pragma unroll
    for (int ks = 0; ks < 8; ++ks) {
      const int kvt = ks >> 1;
      const int qA = 2 * (ks & 1);
      const u32 wA0 = w[kvt][2 * qA], wA1 = w[kvt][2 * qA + 1];
      const u32 wB0 = w[kvt][2 * qA + 2], wB1 = w[kvt][2 * qA + 3];
      const u32 send0 = kh ? wA0 : wB0;
      const u32 send1 = kh ? wA1 : wB1;
      const u32 r0 = (u32)__shfl_xor((int)send0, 32);
      const u32 r1 = (u32)__shfl_xor((int)send1, 32);
      u32 fw[4];
      fw[0] = kh ? r0 : wA0;
      fw[1] = kh ? r1 : wA1;
      fw[2] = kh ? wB0 : r0;
      fw[3] = kh ? wB1 : r1;
      shortx8 pf;
      __builtin_memcpy(&pf, fw, 16);
      __builtin_amdgcn_s_setprio(1);
#pragma unroll
      for (int dt = 0; dt < 4; ++dt) {
        const int vrow = dt * 32 + l31;
        shortx8 vf = *(const shortx8*)(Vs + vrow * 128 + (((ks * 2 + kh) ^ (vrow & 7)) << 3));
        ot[dt] = __builtin_amdgcn_mfma_f32_32x32x16_bf16(vf, pf, ot[dt], 0, 0, 0);
      }
      __builtin_amdgcn_s_setprio(0);
    }
    __syncthreads();
  }

  const float inv = 1.0f / lrun;
  u16* outp = CC + (size_t)qrow * 15360 + head * 128;
#pragma unroll
  for (int dt = 0; dt < 4; ++dt)
#pragma unroll
    for (int g = 0; g < 4; ++g) {
      shortx4 pack;
#pragma unroll
      for (int r = 0; r < 4; ++r) pack[r] = (short)f2bf(ot[dt][4 * g + r] * inv);
      *(shortx4*)(outp + dt * 32 + g * 8 + kh * 4) = pack;
    }
}

// ---------------------------------------------------------------------------
extern "C" void kernel_launch(void* const* d_in, const int* in_sizes, int n_in,
                              void* d_out, int out_size, void* d_ws, size_t ws_size,
                              hipStream_t stream) {
  const float* hs = (const float*)d_in[0];
  const float* cosb = (const float*)d_in[1];
  const float* sinb = (const float*)d_in[2];
  const float* w1 = (const float*)d_in[3];
  const float* wout = (const float*)d_in[4];
  const float* bout = (const float*)d_in[5];
  const float* nqw = (const float*)d_in[6];
  const float* nkw = (const float*)d_in[7];
  float* out = (float*)d_out;

  char* ws = (char*)d_ws;
  u16* X16 = (u16*)ws; ws += (size_t)4096 * 3072 * 2;
  u16* W1T = (u16*)ws; ws += (size_t)33792 * 3072 * 2;
  u16* WOT = (u16*)ws; ws += (size_t)3072 * 15360 * 2;
  u16* H   = (u16*)ws; ws += (size_t)4096 * 33792 * 2;   // qkv (9216-stride); later split-K partials
  u16* Qb  = (u16*)ws; ws += (size_t)24 * 4096 * 128 * 2;
  u16* Kb  = (u16*)ws; ws += (size_t)24 * 4096 * 128 * 2;
  u16* VTb = (u16*)ws; ws += (size_t)24 * 4096 * 128 * 2;
  u16* CC  = (u16*)ws; ws += (size_t)4096 * 15360 * 2;
  float* Pk = (float*)H;  // qkv fully consumed by qkv_prep before gemm8<1> writes

  cast_bf16<<<6144, 256, 0, stream>>>(hs, X16);
  transpose_cast<<<(3072 / 64) * (33792 / 64), 256, 0, stream>>>(w1, W1T, 3072, 33792, 1);
  transpose_cast<<<(15360 / 64) * (3072 / 64), 256, 0, stream>>>(wout, WOT, 15360, 3072, 0);
  gemm8<0><<<(4096 / 256) * (33792 / 256), 512, 0, stream>>>(X16, W1T, H, CC,
                                                             4096, 33792, 3072, 3072);
  qkv_prep<<<dim3(64, 24), 256, 0, stream>>>(H, cosb, sinb, nqw, nkw, Qb, Kb, VTb);
  attn_kernel<<<dim3(32, 24), 256, 0, stream>>>(Qb, Kb, VTb, CC);
  gemm8<1><<<dim3((4096 / 256) * (3072 / 256), 4), 512, 0, stream>>>(
      CC, WOT, Pk, nullptr, 4096, 3072, 15360, 3840);
  reduce_bias<<<(4096 * 3072 / 4) / 256, 256, 0, stream>>>(Pk, bout, out);
}

// Round 13
// 1745.928 us; speedup vs baseline: 1.0123x; 1.0123x over previous
//
#include <hip/hip_runtime.h>

typedef short shortx8 __attribute__((ext_vector_type(8)));   // 8 bf16 (4 VGPRs)
typedef short shortx4 __attribute__((ext_vector_type(4)));   // 4 bf16 (8B)
typedef float floatx4 __attribute__((ext_vector_type(4)));
typedef float floatx16 __attribute__((ext_vector_type(16)));
typedef unsigned short u16;
typedef unsigned int u32;

#define GLB(x) ((const __attribute__((address_space(1))) void*)(x))
#define LDSC(x) ((__attribute__((address_space(3))) void*)(x))
#define BARRIER()                                  \
  do {                                             \
    __builtin_amdgcn_sched_barrier(0);             \
    __builtin_amdgcn_s_barrier();                  \
    __builtin_amdgcn_sched_barrier(0);             \
  } while (0)
#define WAITV6() asm volatile("s_waitcnt vmcnt(6)" ::: "memory")
#define WAITV8() asm volatile("s_waitcnt vmcnt(8)" ::: "memory")
// counted LDS wait: previous register bank complete; just-issued N prefetch
// reads may remain outstanding.  sched_barrier(0) after it per rule #18.
#define WAITLGKM(N)                                          \
  do {                                                       \
    asm volatile("s_waitcnt lgkmcnt(" #N ")");               \
    __builtin_amdgcn_sched_barrier(0);                       \
  } while (0)

__device__ __forceinline__ float bf2f(u16 u) {
  unsigned x = ((unsigned)u) << 16;
  float f;
  __builtin_memcpy(&f, &x, 4);
  return f;
}
__device__ __forceinline__ u16 f2bf(float f) {
  unsigned x;
  __builtin_memcpy(&x, &f, 4);
  x += 0x7fffu + ((x >> 16) & 1u);   // RNE
  return (u16)(x >> 16);
}
__device__ __forceinline__ u32 pk_bf16(float lo, float hi) {
  u32 r;
  asm("v_cvt_pk_bf16_f32 %0, %1, %2" : "=v"(r) : "v"(lo), "v"(hi));
  return r;
}

// ---------------------------------------------------------------------------
// fp32 -> bf16 flat cast (X)
__global__ __launch_bounds__(256) void cast_bf16(const float* __restrict__ src,
                                                 u16* __restrict__ dst) {
  const size_t i = ((size_t)blockIdx.x * 256 + threadIdx.x) << 3;
  floatx4 a = *(const floatx4*)(src + i);
  floatx4 b = *(const floatx4*)(src + i + 4);
  shortx8 o;
#pragma unroll
  for (int e = 0; e < 4; ++e) {
    o[e] = (short)f2bf(a[e]);
    o[e + 4] = (short)f2bf(b[e]);
  }
  *(shortx8*)(dst + i) = o;
}

// ---------------------------------------------------------------------------
// fp32 [R][C] -> bf16 [C][R] tile transpose+cast (64x64 tiles via LDS).
// perm=1: W1 column interleave — dest row order [qkv(9216) | m1/m2 in
// 128-col pairs] so each 256-col GEMM tile holds matching m1/m2 chunks.
__global__ __launch_bounds__(256) void transpose_cast(const float* __restrict__ src,
                                                      u16* __restrict__ dst,
                                                      int R, int C, int perm) {
  __shared__ u16 T[64 * 72];
  const int tiles_c = C >> 6;
  const int r0 = (blockIdx.x / tiles_c) << 6;
  const int c0 = (blockIdx.x % tiles_c) << 6;
  const int tid = threadIdx.x;
  const int rl = tid >> 4;
  const int cb = (tid & 15) << 2;
#pragma unroll
  for (int rr = 0; rr < 4; ++rr) {
    const int row = rr * 16 + rl;
    floatx4 v = *(const floatx4*)(src + (size_t)(r0 + row) * C + c0 + cb);
#pragma unroll
    for (int i = 0; i < 4; ++i) T[(cb + i) * 72 + row] = f2bf(v[i]);
  }
  __syncthreads();
  int dbase = c0;
  if (perm && c0 >= 9216) {
    if (c0 < 21504) { const int u = c0 - 9216;  dbase = 9216 + ((u >> 7) << 8) + (u & 64); }
    else            { const int u = c0 - 21504; dbase = 9216 + ((u >> 7) << 8) + 128 + (u & 64); }
  }
#pragma unroll
  for (int ii = 0; ii < 2; ++ii) {
    const int chunk = tid + (ii << 8);
    const int cr = chunk >> 3;
    const int r8 = (chunk & 7) << 3;
    shortx8 v = *(const shortx8*)(T + cr * 72 + r8);
    *(shortx8*)(dst + (size_t)(dbase + cr) * R + r0 + r8) = v;
  }
}

// ---------------------------------------------------------------------------
// 256x256 8-phase bf16 GEMM with READ-AHEAD register banking.
// B^T layout: C = A[M][Kchunk] * B^T([N][Kchunk]).  16x16x32 MFMA.
// LDS: 2buf x {A,B} x {k0,k1} units of [256][32] (16KB).  Per phase:
//   STAGE 1 unit -> prefetch NEXT phase's frags -> lgkmcnt(N) [prev bank
//   done; N new reads in flight drain UNDER this phase's MFMA] ->
//   sched_barrier -> 16 MFMA -> [vmcnt(6) at q0/q2] -> barrier.
// vmcnt(6) guards: q0-end completes T's k1 units (q1 prefetch reads them);
// q2-end completes T+1's k0 units (q3 prefetch reads buf nxt).
// MODE 0 (GEMM1 fused): bn<36 qkv -> H (stride 9216); bn>=36 MLP tile with
// balanced bidirectional silu(m1)*m2 exchange.  MODE 1: fp32 split-K partial.
template <int MODE>
__global__ __launch_bounds__(512, 2) void gemm8(const u16* __restrict__ A,
                                                const u16* __restrict__ B,
                                                void* __restrict__ Cout,
                                                u16* __restrict__ CC2,
                                                int M, int N, int K, int Ksub) {
  __shared__ u16 lds[8 * 8192];  // [buf][mat][ks][256*32] = 128 KiB

  const int nbm = M >> 8;
  const int nwg = nbm * (N >> 8);
  const int cpx = nwg >> 3;
  const int wg = ((int)blockIdx.x & 7) * cpx + ((int)blockIdx.x >> 3);
  const int bm = wg % nbm;
  const int bn = wg / nbm;
  const int koff = (int)blockIdx.y * Ksub;

  const int tid = threadIdx.x;
  const int lane = tid & 63;
  const int w = tid >> 6;
  const int wm = w >> 2;
  const int wn = w & 3;
  const int l15 = lane & 15;
  const int l4 = lane >> 4;
  const int NT = Ksub >> 6;

  const int lrow = lane >> 2;
  const int lblk = lane & 3;

#define UNIT(buf, mat, ks) (lds + (((buf) * 4 + (mat) * 2 + (ks)) << 13))

  const u16* Abase = A + (size_t)bm * 256 * K + koff;
  const u16* Bbase = B + (size_t)bn * 256 * K + koff;

  auto STAGE = [&](int mat, int ks, int buf, int t) {
    const u16* gb = mat ? Bbase : Abase;
#pragma unroll
    for (int j = 0; j < 2; ++j) {
      const int row = (w * 2 + j) * 16 + lrow;
      const int sblk = lblk ^ ((row >> 1) & 3);
      const u16* src = gb + (size_t)row * K + (t << 6) + (ks << 5) + (sblk << 3);
      __builtin_amdgcn_global_load_lds(GLB(src),
                                       LDSC(UNIT(buf, mat, ks) + ((w * 2 + j) << 9)),
                                       16, 0, 0);
    }
  };
  auto LDA = [&](int mf, int ks, int buf) -> shortx8 {
    const int row = wm * 128 + mf * 16 + l15;
    return *(const shortx8*)(UNIT(buf, 0, ks) + row * 32 + ((l4 ^ ((row >> 1) & 3)) << 3));
  };
  auto LDB = [&](int nf, int ks, int buf) -> shortx8 {
    const int row = wn * 64 + nf * 16 + l15;
    return *(const shortx8*)(UNIT(buf, 1, ks) + row * 32 + ((l4 ^ ((row >> 1) & 3)) << 3));
  };

  floatx4 acc[8][4] = {};
  shortx8 a_cur[4], a_nxt[4], b_cur[4], b_nxt[4];

  // Prologue: tile0 all 4 units + tile1 k0 units (12 loads).
  STAGE(0, 0, 0, 0); STAGE(1, 0, 0, 0);
  STAGE(0, 1, 0, 0); STAGE(1, 1, 0, 0);
  STAGE(0, 0, 1, 1); STAGE(1, 0, 1, 1);
  WAITV8();          // 12-8=4 oldest retire: tile0 k0 units complete
  BARRIER();
#pragma unroll
  for (int m = 0; m < 4; ++m) a_cur[m] = LDA(m, 0, 0);
#pragma unroll
  for (int n = 0; n < 4; ++n) b_cur[n] = LDB(n, 0, 0);

#pragma unroll 2
  for (int T = 0; T < NT; ++T) {
    const int cur = T & 1, nxt = cur ^ 1;
    const int t1 = (T + 1 < NT) ? T + 1 : NT - 1;
    const int t2 = (T + 2 < NT) ? T + 2 : NT - 1;

    // ---- q0: MFMA half0 x k0 (a_cur,b_cur); prefetch a_nxt = half1,k0
    STAGE(0, 1, nxt, t1);
#pragma unroll
    for (int m = 0; m < 4; ++m) a_nxt[m] = LDA(4 + m, 0, cur);
    WAITLGKM(4);
    __builtin_amdgcn_s_setprio(1);
#pragma unroll
    for (int m = 0; m < 4; ++m)
#pragma unroll
      for (int n = 0; n < 4; ++n)
        acc[m][n] = __builtin_amdgcn_mfma_f32_16x16x32_bf16(a_cur[m], b_cur[n], acc[m][n], 0, 0, 0);
    __builtin_amdgcn_s_setprio(0);
    WAITV6();   // retire T's k1 units (q1's prefetch reads them)
    BARRIER();

    // ---- q1: MFMA half1 x k0 (a_nxt,b_cur); prefetch k1 frags
    STAGE(1, 1, nxt, t1);
#pragma unroll
    for (int m = 0; m < 4; ++m) a_cur[m] = LDA(m, 1, cur);
#pragma unroll
    for (int n = 0; n < 4; ++n) b_nxt[n] = LDB(n, 1, cur);
    WAITLGKM(8);
    __builtin_amdgcn_s_setprio(1);
#pragma unroll
    for (int m = 0; m < 4; ++m)
#pragma unroll
      for (int n = 0; n < 4; ++n)
        acc[4 + m][n] = __builtin_amdgcn_mfma_f32_16x16x32_bf16(a_nxt[m], b_cur[n], acc[4 + m][n], 0, 0, 0);
    __builtin_amdgcn_s_setprio(0);
    BARRIER();

    // ---- q2: MFMA half0 x k1 (a_cur,b_nxt); prefetch a_nxt = half1,k1
    STAGE(0, 0, cur, t2);
#pragma unroll
    for (int m = 0; m < 4; ++m) a_nxt[m] = LDA(4 + m, 1, cur);
    WAITLGKM(4);
    __builtin_amdgcn_s_setprio(1);
#pragma unroll
    for (int m = 0; m < 4; ++m)
#pragma unroll
      for (int n = 0; n < 4; ++n)
        acc[m][n] = __builtin_amdgcn_mfma_f32_16x16x32_bf16(a_cur[m], b_nxt[n], acc[m][n], 0, 0, 0);
    __builtin_amdgcn_s_setprio(0);
    WAITV6();   // retire T+1's k0 units (q3's prefetch reads buf nxt)
    BARRIER();

    // ---- q3: MFMA half1 x k1 (a_nxt,b_nxt); prefetch T+1 k0 frags (buf nxt)
    STAGE(1, 0, cur, t2);
#pragma unroll
    for (int m = 0; m < 4; ++m) a_cur[m] = LDA(m, 0, nxt);
#pragma unroll
    for (int n = 0; n < 4; ++n) b_cur[n] = LDB(n, 0, nxt);
    WAITLGKM(8);
    __builtin_amdgcn_s_setprio(1);
#pragma unroll
    for (int m = 0; m < 4; ++m)
#pragma unroll
      for (int n = 0; n < 4; ++n)
        acc[4 + m][n] = __builtin_amdgcn_mfma_f32_16x16x32_bf16(a_nxt[m], b_nxt[n], acc[4 + m][n], 0, 0, 0);
    __builtin_amdgcn_s_setprio(0);
    BARRIER();
  }

  const int orow0 = bm * 256 + wm * 128 + (l4 << 2);
  if (MODE == 0) {
    if (bn < 36) {
      u16* C = (u16*)Cout;
      const int ocol0 = bn * 256 + wn * 64 + l15;
#pragma unroll
      for (int m = 0; m < 8; ++m)
#pragma unroll
        for (int n = 0; n < 4; ++n)
#pragma unroll
          for (int r = 0; r < 4; ++r)
            C[(size_t)(orow0 + m * 16 + r) * 9216 + ocol0 + n * 16] = f2bf(acc[m][n][r]);
    } else {
      // Balanced MLP exchange: per pair region 32KB = [m2 stash | m1 stash]
      __syncthreads();                 // full drain; LDS reusable
      float* buf = (float*)lds + (wm * 2 + (wn & 1)) * 8192;
      if (wn >= 2) {
#pragma unroll
        for (int m = 0; m < 4; ++m)
#pragma unroll
          for (int n = 0; n < 4; ++n) {
            const int chunk = (m * 4 + l4) ^ (l15 & 7);
            *(floatx4*)(buf + (((n * 16 + l15) << 4) + chunk) * 4) = acc[m][n];
          }
      } else {
#pragma unroll
        for (int m = 0; m < 4; ++m)
#pragma unroll
          for (int n = 0; n < 4; ++n) {
            const int chunk = (m * 4 + l4) ^ (l15 & 7);
            *(floatx4*)(buf + 4096 + (((n * 16 + l15) << 4) + chunk) * 4) = acc[4 + m][n];
          }
      }
      __syncthreads();
      const int gcol0 = 3072 + (bn - 36) * 128 + (wn & 1) * 64 + l15;
      if (wn < 2) {
#pragma unroll
        for (int m = 0; m < 4; ++m)
#pragma unroll
          for (int n = 0; n < 4; ++n) {
            const int chunk = (m * 4 + l4) ^ (l15 & 7);
            const floatx4 m2v = *(const floatx4*)(buf + (((n * 16 + l15) << 4) + chunk) * 4);
#pragma unroll
            for (int r = 0; r < 4; ++r) {
              const float m1 = acc[m][n][r];
              const float sg = 1.0f / (1.0f + exp2f(-1.4426950408889634f * m1));
              CC2[(size_t)(orow0 + m * 16 + r) * 15360 + gcol0 + n * 16] =
                  f2bf(m1 * sg * m2v[r]);
            }
          }
      } else {
#pragma unroll
        for (int m = 0; m < 4; ++m)
#pragma unroll
          for (int n = 0; n < 4; ++n) {
            const int chunk = (m * 4 + l4) ^ (l15 & 7);
            const floatx4 m1v = *(const floatx4*)(buf + 4096 + (((n * 16 + l15) << 4) + chunk) * 4);
#pragma unroll
            for (int r = 0; r < 4; ++r) {
              const float m1 = m1v[r];
              const float sg = 1.0f / (1.0f + exp2f(-1.4426950408889634f * m1));
              CC2[(size_t)(orow0 + (4 + m) * 16 + r) * 15360 + gcol0 + n * 16] =
                  f2bf(m1 * sg * acc[4 + m][n][r]);
            }
          }
      }
    }
  } else {
    float* C = (float*)Cout + (size_t)blockIdx.y * M * N;
    const int ocol0 = bn * 256 + wn * 64 + l15;
#pragma unroll
    for (int m = 0; m < 8; ++m)
#pragma unroll
      for (int n = 0; n < 4; ++n)
#pragma unroll
        for (int r = 0; r < 4; ++r)
          C[(size_t)(orow0 + m * 16 + r) * N + ocol0 + n * 16] = acc[m][n][r];
  }
}
#undef UNIT

// ---------------------------------------------------------------------------
// Split-K reduction: out = p0+p1+p2+p3 + bias
__global__ __launch_bounds__(256) void reduce_bias(const float* __restrict__ P,
                                                   const float* __restrict__ bias,
                                                   float* __restrict__ out) {
  const size_t base = ((size_t)blockIdx.x * 256 + threadIdx.x) << 2;
  const size_t stride = (size_t)4096 * 3072;
  floatx4 a = *(const floatx4*)(P + base);
  floatx4 b = *(const floatx4*)(P + stride + base);
  floatx4 c = *(const floatx4*)(P + 2 * stride + base);
  floatx4 d = *(const floatx4*)(P + 3 * stride + base);
  floatx4 bb = *(const floatx4*)(bias + (base % 3072));
  *(floatx4*)(out + base) = a + b + c + d + bb;
}

// ---------------------------------------------------------------------------
// RMSNorm + RoPE + scale fold for Q/K, V transpose to [H][D][S].
#define QSCALE (0.08838834764831845f * 1.4426950408889634f)  // 1/sqrt(128) * log2(e)

__global__ __launch_bounds__(256, 2) void qkv_prep(
    const u16* __restrict__ H, const float* __restrict__ cosb,
    const float* __restrict__ sinb, const float* __restrict__ nqw,
    const float* __restrict__ nkw, u16* __restrict__ Qo, u16* __restrict__ Ko,
    u16* __restrict__ Vo) {
  __shared__ u16 VT[128 * 72];
  const int head = blockIdx.y;
  const int t0 = blockIdx.x << 6;
  const int tid = threadIdx.x;
  const int tl = tid >> 2;
  const int db = (tid & 3) << 5;
  const int token = t0 + tl;

  const u16* hp = H + (size_t)token * 9216 + head * 128 + db;
  shortx8 qv[4], kvv[4], vv[4];
#pragma unroll
  for (int i = 0; i < 4; ++i) {
    qv[i] = *(const shortx8*)(hp + i * 8);
    kvv[i] = *(const shortx8*)(hp + 3072 + i * 8);
    vv[i] = *(const shortx8*)(hp + 6144 + i * 8);
  }
  float qx[32], kx[32];
  float sq = 0.f, sk = 0.f;
#pragma unroll
  for (int i = 0; i < 4; ++i)
#pragma unroll
    for (int j = 0; j < 8; ++j) {
      float a = bf2f((u16)qv[i][j]); qx[i * 8 + j] = a; sq += a * a;
      float b = bf2f((u16)kvv[i][j]); kx[i * 8 + j] = b; sk += b * b;
    }
  sq += __shfl_xor(sq, 1); sq += __shfl_xor(sq, 2);
  sk += __shfl_xor(sk, 1); sk += __shfl_xor(sk, 2);
  const float rq = rsqrtf(sq * (1.0f / 128.0f) + 1e-5f);
  const float rk = rsqrtf(sk * (1.0f / 128.0f) + 1e-5f);

  shortx8 oqv[4], okv[4];
#pragma unroll
  for (int p = 0; p < 16; ++p) {
    const float c = cosb[(size_t)token * 64 + (db >> 1) + p];
    const float s = sinb[(size_t)token * 64 + (db >> 1) + p];
    const int vi = p >> 2, vj = (p & 3) << 1;
    float a1 = qx[2 * p] * rq * nqw[db + 2 * p];
    float a2 = qx[2 * p + 1] * rq * nqw[db + 2 * p + 1];
    oqv[vi][vj] = (short)f2bf((a1 * c - a2 * s) * QSCALE);
    oqv[vi][vj + 1] = (short)f2bf((a2 * c + a1 * s) * QSCALE);
    float b1 = kx[2 * p] * rk * nkw[db + 2 * p];
    float b2 = kx[2 * p + 1] * rk * nkw[db + 2 * p + 1];
    okv[vi][vj] = (short)f2bf(b1 * c - b2 * s);
    okv[vi][vj + 1] = (short)f2bf(b2 * c + b1 * s);
  }
  {
    u16* qo = Qo + (size_t)head * 4096 * 128 + (size_t)token * 128 + db;
    u16* ko = Ko + (size_t)head * 4096 * 128 + (size_t)token * 128 + db;
#pragma unroll
    for (int i = 0; i < 4; ++i) {
      *(shortx8*)(qo + i * 8) = oqv[i];
      *(shortx8*)(ko + i * 8) = okv[i];
    }
  }
#pragma unroll
  for (int i = 0; i < 4; ++i)
#pragma unroll
    for (int j = 0; j < 8; ++j) VT[(db + i * 8 + j) * 72 + tl] = (u16)vv[i][j];
  __syncthreads();
#pragma unroll
  for (int ii = 0; ii < 4; ++ii) {
    const int chunk = tid + (ii << 8);
    const int d = chunk >> 3;
    const int j8 = (chunk & 7) << 3;
    shortx8 v = *(const shortx8*)(VT + d * 72 + j8);
    *(shortx8*)(Vo + (size_t)head * 128 * 4096 + (size_t)d * 4096 + t0 + j8) = v;
  }
}

// ---------------------------------------------------------------------------
// Flash attention, 32x32x16 MFMA, register-resident P (R11-verified).
__global__ __launch_bounds__(256, 2) void attn_kernel(const u16* __restrict__ Qg,
                                                      const u16* __restrict__ Kg,
                                                      const u16* __restrict__ Vg,
                                                      u16* __restrict__ CC) {
  __shared__ u16 Ks[128 * 128];   // [kv][d] swizzled
  __shared__ u16 Vs[128 * 128];   // [d][kv] swizzled

  const int head = blockIdx.y;
  const int q0 = blockIdx.x << 7;
  const int tid = threadIdx.x;
  const int lane = tid & 63;
  const int wave = tid >> 6;
  const int l31 = lane & 31;
  const int kh = lane >> 5;

  const u16* Qh = Qg + (size_t)head * 4096 * 128;
  const u16* Kh = Kg + (size_t)head * 4096 * 128;
  const u16* Vh = Vg + (size_t)head * 128 * 4096;

  const int qrow = q0 + wave * 32 + l31;
  shortx8 qf[8];
#pragma unroll
  for (int ks = 0; ks < 8; ++ks)
    qf[ks] = *(const shortx8*)(Qh + (size_t)qrow * 128 + ks * 16 + kh * 8);

  floatx16 ot[4] = {};
  float mrun = -1e30f, lrun = 0.0f;

  for (int s0 = 0; s0 < 4096; s0 += 128) {
#pragma unroll
    for (int i = 0; i < 8; ++i) {
      const int c = wave * 8 + i;
      const int row = c * 4 + (lane >> 4);
      const int blk = (lane & 15) ^ (row & 7);
      __builtin_amdgcn_global_load_lds(GLB(Kh + (size_t)(s0 + row) * 128 + blk * 8),
                                       LDSC(Ks + c * 512), 16, 0, 0);
    }
#pragma unroll
    for (int i = 0; i < 8; ++i) {
      const int c = wave * 8 + i;
      const int row = c * 4 + (lane >> 4);
      const int blk = (lane & 15) ^ (row & 7);
      __builtin_amdgcn_global_load_lds(GLB(Vh + (size_t)row * 4096 + s0 + blk * 8),
                                       LDSC(Vs + c * 512), 16, 0, 0);
    }
    __syncthreads();

    floatx16 st[4] = {};
    __builtin_amdgcn_s_setprio(1);
#pragma unroll
    for (int kvt = 0; kvt < 4; ++kvt) {
      const int krow = kvt * 32 + l31;
#pragma unroll
      for (int ks = 0; ks < 8; ++ks) {
        shortx8 kf = *(const shortx8*)(Ks + krow * 128 + (((ks * 2 + kh) ^ (krow & 7)) << 3));
        st[kvt] = __builtin_amdgcn_mfma_f32_32x32x16_bf16(kf, qf[ks], st[kvt], 0, 0, 0);
      }
    }
    __builtin_amdgcn_s_setprio(0);

    float vmax = st[0][0];
#pragma unroll
    for (int t = 0; t < 4; ++t)
#pragma unroll
      for (int r = 0; r < 16; ++r) vmax = fmaxf(vmax, st[t][r]);
    vmax = fmaxf(vmax, __shfl_xor(vmax, 32));
    const float mn = fmaxf(mrun, vmax);
    const float alpha = exp2f(mrun - mn);
    mrun = mn;

    float rs = 0.0f;
#pragma unroll
    for (int t = 0; t < 4; ++t)
#pragma unroll
      for (int r = 0; r < 16; ++r) {
        const float p = exp2f(st[t][r] - mn);
        st[t][r] = p;
        rs += p;
      }
    rs += __shfl_xor(rs, 32);
    lrun = lrun * alpha + rs;
    if (__any(alpha < 1.0f)) {
#pragma unroll
      for (int dt = 0; dt < 4; ++dt)
#pragma unroll
        for (int r = 0; r < 16; ++r) ot[dt][r] *= alpha;
    }

    u32 w[4][8];
#pragma unroll
    for (int t = 0; t < 4; ++t)
#pragma unroll
      for (int q = 0; q < 4; ++q) {
        w[t][2 * q] = pk_bf16(st[t][4 * q], st[t][4 * q + 1]);
        w[t][2 * q + 1] = pk_bf16(st[t][4 * q + 2], st[t][4 * q + 3]);
      }

#pragma unroll
    for (int ks = 0; ks < 8; ++ks) {
      const int kvt = ks >> 1;
      const int qA = 2 * (ks & 1);
      const u32 wA0 = w[kvt][2 * qA], wA1 = w[kvt][2 * qA + 1];
      const u32 wB0 = w[kvt][2 * qA + 2], wB1 = w[kvt][2 * qA + 3];
      const u32 send0 = kh ? wA0 : wB0;
      const u32 send1 = kh ? wA1 : wB1;
      const u32 r0 = (u32)__shfl_xor((int)send0, 32);
      const u32 r1 = (u32)__shfl_xor((int)send1, 32);
      u32 fw[4];
      fw[0] = kh ? r0 : wA0;
      fw[1] = kh ? r1 : wA1;
      fw[2] = kh ? wB0 : r0;
      fw[3] = kh ? wB1 : r1;
      shortx8 pf;
      __builtin_memcpy(&pf, fw, 16);
      __builtin_amdgcn_s_setprio(1);
#pragma unroll
      for (int dt = 0; dt < 4; ++dt) {
        const int vrow = dt * 32 + l31;
        shortx8 vf = *(const shortx8*)(Vs + vrow * 128 + (((ks * 2 + kh) ^ (vrow & 7)) << 3));
        ot[dt] = __builtin_amdgcn_mfma_f32_32x32x16_bf16(vf, pf, ot[dt], 0, 0, 0);
      }
      __builtin_amdgcn_s_setprio(0);
    }
    __syncthreads();
  }

  const float inv = 1.0f / lrun;
  u16* outp = CC + (size_t)qrow * 15360 + head * 128;
#pragma unroll
  for (int dt = 0; dt < 4; ++dt)
#pragma unroll
    for (int g = 0; g < 4; ++g) {
      shortx4 pack;
#pragma unroll
      for (int r = 0; r < 4; ++r) pack[r] = (short)f2bf(ot[dt][4 * g + r] * inv);
      *(shortx4*)(outp + dt * 32 + g * 8 + kh * 4) = pack;
    }
}

// ---------------------------------------------------------------------------
extern "C" void kernel_launch(void* const* d_in, const int* in_sizes, int n_in,
                              void* d_out, int out_size, void* d_ws, size_t ws_size,
                              hipStream_t stream) {
  const float* hs = (const float*)d_in[0];
  const float* cosb = (const float*)d_in[1];
  const float* sinb = (const float*)d_in[2];
  const float* w1 = (const float*)d_in[3];
  const float* wout = (const float*)d_in[4];
  const float* bout = (const float*)d_in[5];
  const float* nqw = (const float*)d_in[6];
  const float* nkw = (const float*)d_in[7];
  float* out = (float*)d_out;

  char* ws = (char*)d_ws;
  u16* X16 = (u16*)ws; ws += (size_t)4096 * 3072 * 2;
  u16* W1T = (u16*)ws; ws += (size_t)33792 * 3072 * 2;
  u16* WOT = (u16*)ws; ws += (size_t)3072 * 15360 * 2;
  u16* H   = (u16*)ws; ws += (size_t)4096 * 33792 * 2;   // qkv (9216-stride); later split-K partials
  u16* Qb  = (u16*)ws; ws += (size_t)24 * 4096 * 128 * 2;
  u16* Kb  = (u16*)ws; ws += (size_t)24 * 4096 * 128 * 2;
  u16* VTb = (u16*)ws; ws += (size_t)24 * 4096 * 128 * 2;
  u16* CC  = (u16*)ws; ws += (size_t)4096 * 15360 * 2;
  float* Pk = (float*)H;  // qkv fully consumed by qkv_prep before gemm8<1> writes

  cast_bf16<<<6144, 256, 0, stream>>>(hs, X16);
  transpose_cast<<<(3072 / 64) * (33792 / 64), 256, 0, stream>>>(w1, W1T, 3072, 33792, 1);
  transpose_cast<<<(15360 / 64) * (3072 / 64), 256, 0, stream>>>(wout, WOT, 15360, 3072, 0);
  gemm8<0><<<(4096 / 256) * (33792 / 256), 512, 0, stream>>>(X16, W1T, H, CC,
                                                             4096, 33792, 3072, 3072);
  qkv_prep<<<dim3(64, 24), 256, 0, stream>>>(H, cosb, sinb, nqw, nkw, Qb, Kb, VTb);
  attn_kernel<<<dim3(32, 24), 256, 0, stream>>>(Qb, Kb, VTb, CC);
  gemm8<1><<<dim3((4096 / 256) * (3072 / 256), 4), 512, 0, stream>>>(
      CC, WOT, Pk, nullptr, 4096, 3072, 15360, 3840);
  reduce_bias<<<(4096 * 3072 / 4) / 256, 256, 0, stream>>>(Pk, bout, out);
}